// Round 1
// baseline (12269.347 us; speedup 1.0000x reference)
//
#include <hip/hip_runtime.h>
#include <stdint.h>

namespace {

constexpr int H = 1024;
constexpr int V = 32000;
constexpr int B = 32;
constexpr int T = 64;
constexpr int NPART = V / 256;   // 125 argmax partials per batch row
constexpr int KC = 4;            // k-split for logits kernel
constexpr int KCHUNK = H / KC;   // 256
constexpr long long OUT_LOGITS = (long long)B * T * V;  // 65,536,000

__device__ __forceinline__ uint32_t ord_f32(float f) {
    uint32_t u = __float_as_uint(f);
    return (u & 0x80000000u) ? ~u : (u | 0x80000000u);
}
__device__ __forceinline__ uint64_t pack_key(float val, int idx) {
    // max(key) == max value, ties -> smallest idx (numpy argmax semantics)
    return ((uint64_t)ord_f32(val) << 32) | (uint64_t)(0xFFFFFFFFu - (uint32_t)idx);
}
__device__ __forceinline__ int key_idx(uint64_t k) {
    return (int)(0xFFFFFFFFu - (uint32_t)k);
}
__device__ __forceinline__ uint64_t shfl_xor_u64(uint64_t x, int mask) {
    int lo = __shfl_xor((int)(uint32_t)x, mask);
    int hi = __shfl_xor((int)(uint32_t)(x >> 32), mask);
    return ((uint64_t)(uint32_t)hi << 32) | (uint32_t)lo;
}
__device__ __forceinline__ uint64_t umax64(uint64_t a, uint64_t b) { return a > b ? a : b; }
__device__ __forceinline__ float sigmoidf_(float x) { return 1.0f / (1.0f + expf(-x)); }

// ---------------- W_out transpose: [V][H] -> [H][V] ----------------
__global__ __launch_bounds__(256)
void transpose_kernel(const float* __restrict__ src, float* __restrict__ dst) {
    __shared__ float tile[32][33];
    int vt = blockIdx.x * 32;                 // 0..999
    int kt = blockIdx.y * 32;                 // 0..31
    int tx = threadIdx.x & 31, ty = threadIdx.x >> 5;  // ty 0..7
#pragma unroll
    for (int i = 0; i < 32; i += 8)
        tile[ty + i][tx] = src[(size_t)(vt + ty + i) * H + kt + tx];
    __syncthreads();
#pragma unroll
    for (int i = 0; i < 32; i += 8)
        dst[(size_t)(kt + ty + i) * V + vt + tx] = tile[tx][ty + i];
}

// ---------------- GRU step ----------------
// grid = H blocks (one per output feature j), block = 1024 threads = 16 waves.
// wave w handles batches b0=2w, b1=2w+1 for this j. Weight rows are shared
// across all 16 waves of the block -> L1 reuse.
__global__ __launch_bounds__(1024)
void gru_kernel(const float* __restrict__ h_prev,    // [B][H]
                const float* __restrict__ emb,       // [V][H]
                const float* __restrict__ W_ih,      // [3H][H]
                const float* __restrict__ W_hh,      // [3H][H]
                const float* __restrict__ b_ih,      // [3H]
                const float* __restrict__ b_hh,      // [3H]
                const uint64_t* __restrict__ amax,   // [B][NPART]
                int use_tok,                         // 0 -> tok = SOS(0)
                float* __restrict__ h_new,           // [B][H]
                float* __restrict__ h_newT)          // [H][B]
{
    int j = blockIdx.x;
    int wave = threadIdx.x >> 6;
    int lane = threadIdx.x & 63;
    int b0 = wave * 2, b1 = wave * 2 + 1;

    int tok0 = 0, tok1 = 0;
    if (use_tok) {
        uint64_t k0 = 0, k1 = 0;
        for (int i = lane; i < NPART; i += 64) {
            k0 = umax64(k0, amax[b0 * NPART + i]);
            k1 = umax64(k1, amax[b1 * NPART + i]);
        }
#pragma unroll
        for (int d = 32; d; d >>= 1) {
            k0 = umax64(k0, shfl_xor_u64(k0, d));
            k1 = umax64(k1, shfl_xor_u64(k1, d));
        }
        tok0 = key_idx(k0);
        tok1 = key_idx(k1);
    }

    const float* x0  = emb + (size_t)tok0 * H;
    const float* x1  = emb + (size_t)tok1 * H;
    const float* hp0 = h_prev + (size_t)b0 * H;
    const float* hp1 = h_prev + (size_t)b1 * H;
    const float* wr = W_ih + (size_t)j * H;
    const float* wz = wr + (size_t)H * H;
    const float* wn = wr + (size_t)2 * H * H;
    const float* ur = W_hh + (size_t)j * H;
    const float* uz = ur + (size_t)H * H;
    const float* un = ur + (size_t)2 * H * H;

    float a[12];
#pragma unroll
    for (int i = 0; i < 12; ++i) a[i] = 0.f;

    for (int k = lane; k < H; k += 64) {
        float xv0 = fmaxf(x0[k], 0.f), xv1 = fmaxf(x1[k], 0.f);
        float hv0 = hp0[k], hv1 = hp1[k];
        float w1 = wr[k], w2 = wz[k], w3 = wn[k];
        float u1 = ur[k], u2 = uz[k], u3 = un[k];
        a[0] = fmaf(w1, xv0, a[0]);  a[1]  = fmaf(w2, xv0, a[1]);  a[2]  = fmaf(w3, xv0, a[2]);
        a[3] = fmaf(u1, hv0, a[3]);  a[4]  = fmaf(u2, hv0, a[4]);  a[5]  = fmaf(u3, hv0, a[5]);
        a[6] = fmaf(w1, xv1, a[6]);  a[7]  = fmaf(w2, xv1, a[7]);  a[8]  = fmaf(w3, xv1, a[8]);
        a[9] = fmaf(u1, hv1, a[9]);  a[10] = fmaf(u2, hv1, a[10]); a[11] = fmaf(u3, hv1, a[11]);
    }
#pragma unroll
    for (int i = 0; i < 12; ++i) {
#pragma unroll
        for (int d = 32; d; d >>= 1) a[i] += __shfl_xor(a[i], d);
    }

    if (lane == 0) {
        float bir = b_ih[j], biz = b_ih[j + H], bin = b_ih[j + 2 * H];
        float bhr = b_hh[j], bhz = b_hh[j + H], bhn = b_hh[j + 2 * H];
        {
            float r = sigmoidf_((a[0] + bir) + (a[3] + bhr));
            float z = sigmoidf_((a[1] + biz) + (a[4] + bhz));
            float n = tanhf((a[2] + bin) + r * (a[5] + bhn));
            float o = (1.f - z) * n + z * hp0[j];
            h_new[(size_t)b0 * H + j] = o;
            h_newT[(size_t)j * B + b0] = o;
        }
        {
            float r = sigmoidf_((a[6] + bir) + (a[9] + bhr));
            float z = sigmoidf_((a[7] + biz) + (a[10] + bhz));
            float n = tanhf((a[8] + bin) + r * (a[11] + bhn));
            float o = (1.f - z) * n + z * hp1[j];
            h_new[(size_t)b1 * H + j] = o;
            h_newT[(size_t)j * B + b1] = o;
        }
    }
}

// ---------------- logits: partial GEMV-batch ----------------
// wave = (v-tile of 64, k-chunk of 256). Lanes = 64 consecutive v (coalesced
// weight loads when W is transposed); 32 batch accumulators per lane fed by
// wave-uniform h values (scalar loads). part[kc][b][v].
__global__ __launch_bounds__(256)
void logits_kernel(const float* __restrict__ Wmat, long long sK, long long sV,
                   const float* __restrict__ hT,   // [H][B]
                   float* __restrict__ part)       // [KC][B][V]
{
    int wid  = blockIdx.x * 4 + (threadIdx.x >> 6);   // 0..1999
    int lane = threadIdx.x & 63;
    int vt = wid % 500, kc = wid / 500;
    int v  = vt * 64 + lane;
    int kb = kc * KCHUNK;

    const float* wp = Wmat + (long long)kb * sK + (long long)v * sV;
    const float* hp = hT + (size_t)kb * B;

    float acc[B];
#pragma unroll
    for (int b = 0; b < B; ++b) acc[b] = 0.f;

    for (int k = 0; k < KCHUNK; ++k) {
        float w = *wp;
        wp += sK;
#pragma unroll
        for (int b = 0; b < B; ++b) acc[b] = fmaf(hp[b], w, acc[b]);
        hp += B;
    }
#pragma unroll
    for (int b = 0; b < B; ++b)
        part[((size_t)kc * B + b) * V + v] = acc[b];
}

// ---------------- logits finish: sum partials + bias, store, argmax partials ----------------
__global__ __launch_bounds__(256)
void logits_finish_kernel(const float* __restrict__ part,
                          const float* __restrict__ b_out,
                          float* __restrict__ out,          // d_out logits region
                          int t,
                          uint64_t* __restrict__ amax)      // [B][NPART]
{
    int b  = blockIdx.x / NPART;
    int vb = blockIdx.x % NPART;
    int v  = vb * 256 + threadIdx.x;

    float s = part[((size_t)0 * B + b) * V + v]
            + part[((size_t)1 * B + b) * V + v]
            + part[((size_t)2 * B + b) * V + v]
            + part[((size_t)3 * B + b) * V + v]
            + b_out[v];
    out[((size_t)b * T + t) * V + v] = s;

    uint64_t key = pack_key(s, v);
#pragma unroll
    for (int d = 32; d; d >>= 1) key = umax64(key, shfl_xor_u64(key, d));

    __shared__ uint64_t lds[4];
    int lane = threadIdx.x & 63, wave = threadIdx.x >> 6;
    if (lane == 0) lds[wave] = key;
    __syncthreads();
    if (threadIdx.x == 0)
        amax[(size_t)b * NPART + vb] = umax64(umax64(lds[0], lds[1]), umax64(lds[2], lds[3]));
}

// ---------------- final log-softmax over each [b][t] row ----------------
__global__ __launch_bounds__(256)
void logsoftmax_kernel(float* __restrict__ out) {
    size_t row = (size_t)blockIdx.x * V;
    int lane = threadIdx.x & 63, wave = threadIdx.x >> 6;
    __shared__ float red[4];

    float m = -INFINITY;
    for (int v = threadIdx.x; v < V; v += 256) m = fmaxf(m, out[row + v]);
#pragma unroll
    for (int d = 32; d; d >>= 1) m = fmaxf(m, __shfl_xor(m, d));
    if (lane == 0) red[wave] = m;
    __syncthreads();
    float M = fmaxf(fmaxf(red[0], red[1]), fmaxf(red[2], red[3]));
    __syncthreads();

    float s = 0.f;
    for (int v = threadIdx.x; v < V; v += 256) s += expf(out[row + v] - M);
#pragma unroll
    for (int d = 32; d; d >>= 1) s += __shfl_xor(s, d);
    if (lane == 0) red[wave] = s;
    __syncthreads();
    float S = red[0] + red[1] + red[2] + red[3];

    float L = M + logf(S);
    for (int v = threadIdx.x; v < V; v += 256) out[row + v] -= L;
}

// ---------------- copy final hidden state to output tail ----------------
__global__ __launch_bounds__(256)
void copy_h_kernel(const float* __restrict__ h, float* __restrict__ out) {
    int i = blockIdx.x * 256 + threadIdx.x;   // 32768 elements
    out[OUT_LOGITS + i] = h[i];
}

}  // namespace

extern "C" void kernel_launch(void* const* d_in, const int* in_sizes, int n_in,
                              void* d_out, int out_size, void* d_ws, size_t ws_size,
                              hipStream_t stream) {
    // d_in: 0 encoder_outputs (unused), 1 encoder_hidden [1,B,H], 2 emb [V,H],
    //       3 W_ih [3H,H], 4 W_hh [3H,H], 5 b_ih [3H], 6 b_hh [3H],
    //       7 W_out [V,H], 8 b_out [V]
    const float* enc_hidden = (const float*)d_in[1];
    const float* emb   = (const float*)d_in[2];
    const float* W_ih  = (const float*)d_in[3];
    const float* W_hh  = (const float*)d_in[4];
    const float* b_ih  = (const float*)d_in[5];
    const float* b_hh  = (const float*)d_in[6];
    const float* W_out = (const float*)d_in[7];
    const float* b_out = (const float*)d_in[8];
    float* out = (float*)d_out;

    float* ws = (float*)d_ws;
    // ws layout (floats): [WT (V*H) if big] | hA | hB | hTA | hTB | part | amax(u64)
    const size_t WT_FLOATS   = (size_t)V * H;            // 32,768,000
    const size_t SMALL_FLOATS = 4 * 32768 + (size_t)KC * B * V + 2 * (size_t)B * NPART;
    bool big = ws_size >= (WT_FLOATS + SMALL_FLOATS) * sizeof(float);

    float* WT   = ws;
    float* base = big ? ws + WT_FLOATS : ws;
    float* hA   = base;
    float* hB   = base + 32768;
    float* hTA  = base + 2 * 32768;
    float* hTB  = base + 3 * 32768;
    float* part = base + 4 * 32768;
    uint64_t* amax = (uint64_t*)(part + (size_t)KC * B * V);

    const float* Wm;
    long long sK, sV;
    if (big) {
        transpose_kernel<<<dim3(1000, 32), 256, 0, stream>>>(W_out, WT);
        Wm = WT; sK = V; sV = 1;        // WT[k][v]: coalesced over v-lanes
    } else {
        Wm = W_out; sK = 1; sV = H;     // fallback: uncoalesced but correct
    }

    for (int t = 0; t < T; ++t) {
        const float* hp = (t == 0) ? enc_hidden : ((t & 1) ? hA : hB);
        float* hn  = (t & 1) ? hB : hA;
        float* hnT = (t & 1) ? hTB : hTA;
        gru_kernel<<<H, 1024, 0, stream>>>(hp, emb, W_ih, W_hh, b_ih, b_hh,
                                           amax, t == 0 ? 0 : 1, hn, hnT);
        logits_kernel<<<500, 256, 0, stream>>>(Wm, sK, sV, hnT, part);
        logits_finish_kernel<<<B * NPART, 256, 0, stream>>>(part, b_out, out, t, amax);
    }

    logsoftmax_kernel<<<B * T, 256, 0, stream>>>(out);
    copy_h_kernel<<<32768 / 256, 256, 0, stream>>>(hB, out);  // t=63 wrote hB
}

// Round 2
// 10790.912 us; speedup vs baseline: 1.1370x; 1.1370x over previous
//
#include <hip/hip_runtime.h>
#include <stdint.h>

namespace {

constexpr int H = 1024;
constexpr int V = 32000;
constexpr int B = 32;
constexpr int T = 64;
constexpr int NPART = V / 64;    // 500 argmax partials per batch row (one per v-tile)
constexpr long long OUT_LOGITS = (long long)B * T * V;  // 65,536,000

__device__ __forceinline__ uint32_t ord_f32(float f) {
    uint32_t u = __float_as_uint(f);
    return (u & 0x80000000u) ? ~u : (u | 0x80000000u);
}
__device__ __forceinline__ uint64_t pack_key(float val, int idx) {
    // max(key) == max value, ties -> smallest idx (numpy argmax semantics)
    return ((uint64_t)ord_f32(val) << 32) | (uint64_t)(0xFFFFFFFFu - (uint32_t)idx);
}
__device__ __forceinline__ int key_idx(uint64_t k) {
    return (int)(0xFFFFFFFFu - (uint32_t)k);
}
__device__ __forceinline__ uint64_t shfl_xor_u64(uint64_t x, int mask) {
    int lo = __shfl_xor((int)(uint32_t)x, mask);
    int hi = __shfl_xor((int)(uint32_t)(x >> 32), mask);
    return ((uint64_t)(uint32_t)hi << 32) | (uint32_t)lo;
}
__device__ __forceinline__ uint64_t umax64(uint64_t a, uint64_t b) { return a > b ? a : b; }
__device__ __forceinline__ float sigmoidf_(float x) { return 1.0f / (1.0f + expf(-x)); }

// ---------------- W_out transpose: [V][H] -> [H][V] ----------------
__global__ __launch_bounds__(256)
void transpose_kernel(const float* __restrict__ src, float* __restrict__ dst) {
    __shared__ float tile[32][33];
    int vt = blockIdx.x * 32;                 // 0..999
    int kt = blockIdx.y * 32;                 // 0..31
    int tx = threadIdx.x & 31, ty = threadIdx.x >> 5;  // ty 0..7
#pragma unroll
    for (int i = 0; i < 32; i += 8)
        tile[ty + i][tx] = src[(size_t)(vt + ty + i) * H + kt + tx];
    __syncthreads();
#pragma unroll
    for (int i = 0; i < 32; i += 8)
        dst[(size_t)(kt + ty + i) * V + vt + tx] = tile[tx][ty + i];
}

// ---------------- GRU step (math identical to round-1 passing version) ----------------
__global__ __launch_bounds__(1024)
void gru_kernel(const float* __restrict__ h_prev,    // [B][H]
                const float* __restrict__ emb,       // [V][H]
                const float* __restrict__ W_ih,      // [3H][H]
                const float* __restrict__ W_hh,      // [3H][H]
                const float* __restrict__ b_ih,      // [3H]
                const float* __restrict__ b_hh,      // [3H]
                const uint64_t* __restrict__ amax,   // [B][NPART]
                int use_tok,                         // 0 -> tok = SOS(0)
                float* __restrict__ h_new,           // [B][H]
                float* __restrict__ h_newT)          // [H][B]
{
    int j = blockIdx.x;
    int wave = threadIdx.x >> 6;
    int lane = threadIdx.x & 63;
    int b0 = wave * 2, b1 = wave * 2 + 1;

    int tok0 = 0, tok1 = 0;
    if (use_tok) {
        uint64_t k0 = 0, k1 = 0;
        for (int i = lane; i < NPART; i += 64) {
            k0 = umax64(k0, amax[b0 * NPART + i]);
            k1 = umax64(k1, amax[b1 * NPART + i]);
        }
#pragma unroll
        for (int d = 32; d; d >>= 1) {
            k0 = umax64(k0, shfl_xor_u64(k0, d));
            k1 = umax64(k1, shfl_xor_u64(k1, d));
        }
        tok0 = key_idx(k0);
        tok1 = key_idx(k1);
    }

    const float* x0  = emb + (size_t)tok0 * H;
    const float* x1  = emb + (size_t)tok1 * H;
    const float* hp0 = h_prev + (size_t)b0 * H;
    const float* hp1 = h_prev + (size_t)b1 * H;
    const float* wr = W_ih + (size_t)j * H;
    const float* wz = wr + (size_t)H * H;
    const float* wn = wr + (size_t)2 * H * H;
    const float* ur = W_hh + (size_t)j * H;
    const float* uz = ur + (size_t)H * H;
    const float* un = ur + (size_t)2 * H * H;

    float a[12];
#pragma unroll
    for (int i = 0; i < 12; ++i) a[i] = 0.f;

    for (int k = lane; k < H; k += 64) {
        float xv0 = fmaxf(x0[k], 0.f), xv1 = fmaxf(x1[k], 0.f);
        float hv0 = hp0[k], hv1 = hp1[k];
        float w1 = wr[k], w2 = wz[k], w3 = wn[k];
        float u1 = ur[k], u2 = uz[k], u3 = un[k];
        a[0] = fmaf(w1, xv0, a[0]);  a[1]  = fmaf(w2, xv0, a[1]);  a[2]  = fmaf(w3, xv0, a[2]);
        a[3] = fmaf(u1, hv0, a[3]);  a[4]  = fmaf(u2, hv0, a[4]);  a[5]  = fmaf(u3, hv0, a[5]);
        a[6] = fmaf(w1, xv1, a[6]);  a[7]  = fmaf(w2, xv1, a[7]);  a[8]  = fmaf(w3, xv1, a[8]);
        a[9] = fmaf(u1, hv1, a[9]);  a[10] = fmaf(u2, hv1, a[10]); a[11] = fmaf(u3, hv1, a[11]);
    }
#pragma unroll
    for (int i = 0; i < 12; ++i) {
#pragma unroll
        for (int d = 32; d; d >>= 1) a[i] += __shfl_xor(a[i], d);
    }

    if (lane == 0) {
        float bir = b_ih[j], biz = b_ih[j + H], bin = b_ih[j + 2 * H];
        float bhr = b_hh[j], bhz = b_hh[j + H], bhn = b_hh[j + 2 * H];
        {
            float r = sigmoidf_((a[0] + bir) + (a[3] + bhr));
            float z = sigmoidf_((a[1] + biz) + (a[4] + bhz));
            float n = tanhf((a[2] + bin) + r * (a[5] + bhn));
            float o = (1.f - z) * n + z * hp0[j];
            h_new[(size_t)b0 * H + j] = o;
            h_newT[(size_t)j * B + b0] = o;
        }
        {
            float r = sigmoidf_((a[6] + bir) + (a[9] + bhr));
            float z = sigmoidf_((a[7] + biz) + (a[10] + bhz));
            float n = tanhf((a[8] + bin) + r * (a[11] + bhn));
            float o = (1.f - z) * n + z * hp1[j];
            h_new[(size_t)b1 * H + j] = o;
            h_newT[(size_t)j * B + b1] = o;
        }
    }
}

// ---------------- fused logits + bias + store + argmax partials ----------------
// grid = 500 blocks (one per 64-wide v-tile), block = 256 = 4 waves.
// Wave kc handles k-chunk [kc*256, kc*256+256) for all 32 batches, lane = v.
// Per k: 1 coalesced w load (256 B/wave) + 8 wave-uniform float4 h loads + 32 FMAs.
// Partials reduced via LDS in the exact ((p0+p1)+p2)+p3 + bias order of round 1
// -> bit-identical logits -> identical argmax trajectory.
__global__ __launch_bounds__(256)
void logits_fused_kernel(const float* __restrict__ WT,   // [H][V]
                         const float* __restrict__ hT,   // [H][B]
                         const float* __restrict__ b_out,
                         float* __restrict__ out,        // d_out logits region
                         int t,
                         uint64_t* __restrict__ amax)    // [B][NPART]
{
    const int vt   = blockIdx.x;           // 0..499
    const int wave = threadIdx.x >> 6;     // = k-chunk 0..3
    const int lane = threadIdx.x & 63;
    const int kb   = wave * 256;
    const int v    = vt * 64 + lane;

    const float*  wp = WT + (size_t)kb * V + v;
    const float4* hp = (const float4*)(hT + (size_t)kb * B);

    float acc[32];
#pragma unroll
    for (int b = 0; b < 32; ++b) acc[b] = 0.f;

#pragma unroll 8
    for (int k = 0; k < 256; ++k) {
        float w = *wp;
        wp += V;
        float4 hv[8];
#pragma unroll
        for (int q = 0; q < 8; ++q) hv[q] = hp[q];
        hp += 8;
#pragma unroll
        for (int q = 0; q < 8; ++q) {
            acc[4 * q + 0] = fmaf(hv[q].x, w, acc[4 * q + 0]);
            acc[4 * q + 1] = fmaf(hv[q].y, w, acc[4 * q + 1]);
            acc[4 * q + 2] = fmaf(hv[q].z, w, acc[4 * q + 2]);
            acc[4 * q + 3] = fmaf(hv[q].w, w, acc[4 * q + 3]);
        }
    }

    __shared__ float red[4][B * 64];       // 32 KB
#pragma unroll
    for (int b = 0; b < 32; ++b) red[wave][b * 64 + lane] = acc[b];
    __syncthreads();

    // epilogue: wave w handles batches [8w, 8w+8) over the tile's 64 v
    const float bias = b_out[v];
#pragma unroll
    for (int bi = 0; bi < 8; ++bi) {
        int b = wave * 8 + bi;
        int c = b * 64 + lane;
        float s = (((red[0][c] + red[1][c]) + red[2][c]) + red[3][c]) + bias;
        out[((size_t)b * T + t) * V + v] = s;

        uint64_t key = pack_key(s, v);
#pragma unroll
        for (int d = 32; d; d >>= 1) key = umax64(key, shfl_xor_u64(key, d));
        if (lane == 0) amax[(size_t)b * NPART + vt] = key;
    }
}

// ---------------- final log-softmax over each [b][t] row ----------------
__global__ __launch_bounds__(256)
void logsoftmax_kernel(float* __restrict__ out) {
    size_t row = (size_t)blockIdx.x * V;
    int lane = threadIdx.x & 63, wave = threadIdx.x >> 6;
    __shared__ float red[4];

    float m = -INFINITY;
    for (int v = threadIdx.x; v < V; v += 256) m = fmaxf(m, out[row + v]);
#pragma unroll
    for (int d = 32; d; d >>= 1) m = fmaxf(m, __shfl_xor(m, d));
    if (lane == 0) red[wave] = m;
    __syncthreads();
    float M = fmaxf(fmaxf(red[0], red[1]), fmaxf(red[2], red[3]));
    __syncthreads();

    float s = 0.f;
    for (int v = threadIdx.x; v < V; v += 256) s += expf(out[row + v] - M);
#pragma unroll
    for (int d = 32; d; d >>= 1) s += __shfl_xor(s, d);
    if (lane == 0) red[wave] = s;
    __syncthreads();
    float S = red[0] + red[1] + red[2] + red[3];

    float L = M + logf(S);
    for (int v = threadIdx.x; v < V; v += 256) out[row + v] -= L;
}

// ---------------- copy final hidden state to output tail ----------------
__global__ __launch_bounds__(256)
void copy_h_kernel(const float* __restrict__ h, float* __restrict__ out) {
    int i = blockIdx.x * 256 + threadIdx.x;   // 32768 elements
    out[OUT_LOGITS + i] = h[i];
}

}  // namespace

extern "C" void kernel_launch(void* const* d_in, const int* in_sizes, int n_in,
                              void* d_out, int out_size, void* d_ws, size_t ws_size,
                              hipStream_t stream) {
    // d_in: 0 encoder_outputs (unused), 1 encoder_hidden [1,B,H], 2 emb [V,H],
    //       3 W_ih [3H,H], 4 W_hh [3H,H], 5 b_ih [3H], 6 b_hh [3H],
    //       7 W_out [V,H], 8 b_out [V]
    const float* enc_hidden = (const float*)d_in[1];
    const float* emb   = (const float*)d_in[2];
    const float* W_ih  = (const float*)d_in[3];
    const float* W_hh  = (const float*)d_in[4];
    const float* b_ih  = (const float*)d_in[5];
    const float* b_hh  = (const float*)d_in[6];
    const float* W_out = (const float*)d_in[7];
    const float* b_out = (const float*)d_in[8];
    float* out = (float*)d_out;

    float* ws = (float*)d_ws;
    // ws layout (floats): WT (V*H) | hA | hB | hTA | hTB | amax(u64 [B][NPART])
    const size_t WT_FLOATS = (size_t)V * H;              // 32,768,000
    float* WT   = ws;
    float* hA   = ws + WT_FLOATS;
    float* hB   = hA + 32768;
    float* hTA  = hB + 32768;
    float* hTB  = hTA + 32768;
    uint64_t* amax = (uint64_t*)(hTB + 32768);           // 32*500*8 B = 128 KB

    transpose_kernel<<<dim3(1000, 32), 256, 0, stream>>>(W_out, WT);

    for (int t = 0; t < T; ++t) {
        const float* hp = (t == 0) ? enc_hidden : ((t & 1) ? hA : hB);
        float* hn  = (t & 1) ? hB : hA;
        float* hnT = (t & 1) ? hTB : hTA;
        gru_kernel<<<H, 1024, 0, stream>>>(hp, emb, W_ih, W_hh, b_ih, b_hh,
                                           amax, t == 0 ? 0 : 1, hn, hnT);
        logits_fused_kernel<<<500, 256, 0, stream>>>(WT, hnT, b_out, out, t, amax);
    }

    logsoftmax_kernel<<<B * T, 256, 0, stream>>>(out);
    copy_h_kernel<<<32768 / 256, 256, 0, stream>>>(hB, out);  // t=63 wrote hB
}

// Round 3
// 10563.564 us; speedup vs baseline: 1.1615x; 1.0215x over previous
//
#include <hip/hip_runtime.h>
#include <stdint.h>

namespace {

constexpr int H = 1024;
constexpr int V = 32000;
constexpr int B = 32;
constexpr int T = 64;
constexpr int NPART = V / 64;    // 500 argmax partials per batch row (one per v-tile)
constexpr long long OUT_LOGITS = (long long)B * T * V;  // 65,536,000

__device__ __forceinline__ uint32_t ord_f32(float f) {
    uint32_t u = __float_as_uint(f);
    return (u & 0x80000000u) ? ~u : (u | 0x80000000u);
}
__device__ __forceinline__ uint64_t pack_key(float val, int idx) {
    // max(key) == max value, ties -> smallest idx (numpy argmax semantics)
    return ((uint64_t)ord_f32(val) << 32) | (uint64_t)(0xFFFFFFFFu - (uint32_t)idx);
}
__device__ __forceinline__ int key_idx(uint64_t k) {
    return (int)(0xFFFFFFFFu - (uint32_t)k);
}
__device__ __forceinline__ uint64_t shfl_xor_u64(uint64_t x, int mask) {
    int lo = __shfl_xor((int)(uint32_t)x, mask);
    int hi = __shfl_xor((int)(uint32_t)(x >> 32), mask);
    return ((uint64_t)(uint32_t)hi << 32) | (uint32_t)lo;
}
__device__ __forceinline__ uint64_t umax64(uint64_t a, uint64_t b) { return a > b ? a : b; }
__device__ __forceinline__ float sigmoidf_(float x) { return 1.0f / (1.0f + expf(-x)); }

// ---------------- W_out transpose: [V][H] -> [H][V] ----------------
__global__ __launch_bounds__(256)
void transpose_kernel(const float* __restrict__ src, float* __restrict__ dst) {
    __shared__ float tile[32][33];
    int vt = blockIdx.x * 32;                 // 0..999
    int kt = blockIdx.y * 32;                 // 0..31
    int tx = threadIdx.x & 31, ty = threadIdx.x >> 5;  // ty 0..7
#pragma unroll
    for (int i = 0; i < 32; i += 8)
        tile[ty + i][tx] = src[(size_t)(vt + ty + i) * H + kt + tx];
    __syncthreads();
#pragma unroll
    for (int i = 0; i < 32; i += 8)
        dst[(size_t)(kt + ty + i) * V + vt + tx] = tile[tx][ty + i];
}

// ---------------- GRU step (unchanged from round-2 passing version) ----------------
__global__ __launch_bounds__(1024)
void gru_kernel(const float* __restrict__ h_prev,    // [B][H]
                const float* __restrict__ emb,       // [V][H]
                const float* __restrict__ W_ih,      // [3H][H]
                const float* __restrict__ W_hh,      // [3H][H]
                const float* __restrict__ b_ih,      // [3H]
                const float* __restrict__ b_hh,      // [3H]
                const uint64_t* __restrict__ amax,   // [B][NPART]
                int use_tok,                         // 0 -> tok = SOS(0)
                float* __restrict__ h_new,           // [B][H]
                float* __restrict__ h_newT)          // [H][B]
{
    int j = blockIdx.x;
    int wave = threadIdx.x >> 6;
    int lane = threadIdx.x & 63;
    int b0 = wave * 2, b1 = wave * 2 + 1;

    int tok0 = 0, tok1 = 0;
    if (use_tok) {
        uint64_t k0 = 0, k1 = 0;
        for (int i = lane; i < NPART; i += 64) {
            k0 = umax64(k0, amax[b0 * NPART + i]);
            k1 = umax64(k1, amax[b1 * NPART + i]);
        }
#pragma unroll
        for (int d = 32; d; d >>= 1) {
            k0 = umax64(k0, shfl_xor_u64(k0, d));
            k1 = umax64(k1, shfl_xor_u64(k1, d));
        }
        tok0 = key_idx(k0);
        tok1 = key_idx(k1);
    }

    const float* x0  = emb + (size_t)tok0 * H;
    const float* x1  = emb + (size_t)tok1 * H;
    const float* hp0 = h_prev + (size_t)b0 * H;
    const float* hp1 = h_prev + (size_t)b1 * H;
    const float* wr = W_ih + (size_t)j * H;
    const float* wz = wr + (size_t)H * H;
    const float* wn = wr + (size_t)2 * H * H;
    const float* ur = W_hh + (size_t)j * H;
    const float* uz = ur + (size_t)H * H;
    const float* un = ur + (size_t)2 * H * H;

    float a[12];
#pragma unroll
    for (int i = 0; i < 12; ++i) a[i] = 0.f;

    for (int k = lane; k < H; k += 64) {
        float xv0 = fmaxf(x0[k], 0.f), xv1 = fmaxf(x1[k], 0.f);
        float hv0 = hp0[k], hv1 = hp1[k];
        float w1 = wr[k], w2 = wz[k], w3 = wn[k];
        float u1 = ur[k], u2 = uz[k], u3 = un[k];
        a[0] = fmaf(w1, xv0, a[0]);  a[1]  = fmaf(w2, xv0, a[1]);  a[2]  = fmaf(w3, xv0, a[2]);
        a[3] = fmaf(u1, hv0, a[3]);  a[4]  = fmaf(u2, hv0, a[4]);  a[5]  = fmaf(u3, hv0, a[5]);
        a[6] = fmaf(w1, xv1, a[6]);  a[7]  = fmaf(w2, xv1, a[7]);  a[8]  = fmaf(w3, xv1, a[8]);
        a[9] = fmaf(u1, hv1, a[9]);  a[10] = fmaf(u2, hv1, a[10]); a[11] = fmaf(u3, hv1, a[11]);
    }
#pragma unroll
    for (int i = 0; i < 12; ++i) {
#pragma unroll
        for (int d = 32; d; d >>= 1) a[i] += __shfl_xor(a[i], d);
    }

    if (lane == 0) {
        float bir = b_ih[j], biz = b_ih[j + H], bin = b_ih[j + 2 * H];
        float bhr = b_hh[j], bhz = b_hh[j + H], bhn = b_hh[j + 2 * H];
        {
            float r = sigmoidf_((a[0] + bir) + (a[3] + bhr));
            float z = sigmoidf_((a[1] + biz) + (a[4] + bhz));
            float n = tanhf((a[2] + bin) + r * (a[5] + bhn));
            float o = (1.f - z) * n + z * hp0[j];
            h_new[(size_t)b0 * H + j] = o;
            h_newT[(size_t)j * B + b0] = o;
        }
        {
            float r = sigmoidf_((a[6] + bir) + (a[9] + bhr));
            float z = sigmoidf_((a[7] + biz) + (a[10] + bhz));
            float n = tanhf((a[8] + bin) + r * (a[11] + bhn));
            float o = (1.f - z) * n + z * hp1[j];
            h_new[(size_t)b1 * H + j] = o;
            h_newT[(size_t)j * B + b1] = o;
        }
    }
}

// ---------------- fused logits + bias + store + argmax partials (v2) ----------------
// grid = 500 blocks (one per 64-wide v-tile), block = 512 = 8 waves.
// Wave w handles k-chunk [w*128, w*128+128) for all 32 batches, lane = v.
// __launch_bounds__(512,4): VGPR <= 128 so 2 blocks (16 waves) fit per CU
// alongside the 64 KB LDS reduce buffer -> 4 waves/SIMD for L3-latency hiding.
// Unroll kept at 2 so natural pressure (~acc32+hv32+addr) stays under the cap:
// round-2's unroll-8 wanted 256+ VGPRs of h in flight (spill/serialize).
__global__ __launch_bounds__(512, 4)
void logits_fused_kernel(const float* __restrict__ WT,   // [H][V]
                         const float* __restrict__ hT,   // [H][B]
                         const float* __restrict__ b_out,
                         float* __restrict__ out,        // d_out logits region
                         int t,
                         uint64_t* __restrict__ amax)    // [B][NPART]
{
    const int vt   = blockIdx.x;           // 0..499
    const int wave = threadIdx.x >> 6;     // = k-chunk 0..7
    const int lane = threadIdx.x & 63;
    const int kb   = wave * 128;
    const int v    = vt * 64 + lane;

    const float*  wp = WT + (size_t)kb * V + v;
    const float4* hp = (const float4*)(hT + (size_t)kb * B);

    float acc[32];
#pragma unroll
    for (int b = 0; b < 32; ++b) acc[b] = 0.f;

    // prefetch first w; loop prefetches next row while FMA-ing current.
    // NOTE: final prefetch (wave 7, k=127) reads 1 row past WT -> lands in the
    // h-scratch that directly follows WT in d_ws (in-bounds, value unused).
    float wcur = *wp;
    wp += V;

#pragma unroll 2
    for (int k = 0; k < 128; ++k) {
        float wnxt = *wp;
        wp += V;
        float4 hv[8];
#pragma unroll
        for (int q = 0; q < 8; ++q) hv[q] = hp[q];
        hp += 8;
#pragma unroll
        for (int q = 0; q < 8; ++q) {
            acc[4 * q + 0] = fmaf(hv[q].x, wcur, acc[4 * q + 0]);
            acc[4 * q + 1] = fmaf(hv[q].y, wcur, acc[4 * q + 1]);
            acc[4 * q + 2] = fmaf(hv[q].z, wcur, acc[4 * q + 2]);
            acc[4 * q + 3] = fmaf(hv[q].w, wcur, acc[4 * q + 3]);
        }
        wcur = wnxt;
    }

    __shared__ float red[8][B * 64];       // 64 KB
#pragma unroll
    for (int b = 0; b < 32; ++b) red[wave][b * 64 + lane] = acc[b];
    __syncthreads();

    // epilogue: wave w handles batches [4w, 4w+4) over the tile's 64 v
    const float bias = b_out[v];
#pragma unroll
    for (int bi = 0; bi < 4; ++bi) {
        int b = wave * 4 + bi;
        int c = b * 64 + lane;
        float s = red[0][c];
#pragma unroll
        for (int cc = 1; cc < 8; ++cc) s += red[cc][c];
        s += bias;
        out[((size_t)b * T + t) * V + v] = s;

        uint64_t key = pack_key(s, v);
#pragma unroll
        for (int d = 32; d; d >>= 1) key = umax64(key, shfl_xor_u64(key, d));
        if (lane == 0) amax[(size_t)b * NPART + vt] = key;
    }
}

// ---------------- final log-softmax over each [b][t] row ----------------
__global__ __launch_bounds__(256)
void logsoftmax_kernel(float* __restrict__ out) {
    size_t row = (size_t)blockIdx.x * V;
    int lane = threadIdx.x & 63, wave = threadIdx.x >> 6;
    __shared__ float red[4];

    float m = -INFINITY;
    for (int v = threadIdx.x; v < V; v += 256) m = fmaxf(m, out[row + v]);
#pragma unroll
    for (int d = 32; d; d >>= 1) m = fmaxf(m, __shfl_xor(m, d));
    if (lane == 0) red[wave] = m;
    __syncthreads();
    float M = fmaxf(fmaxf(red[0], red[1]), fmaxf(red[2], red[3]));
    __syncthreads();

    float s = 0.f;
    for (int v = threadIdx.x; v < V; v += 256) s += expf(out[row + v] - M);
#pragma unroll
    for (int d = 32; d; d >>= 1) s += __shfl_xor(s, d);
    if (lane == 0) red[wave] = s;
    __syncthreads();
    float S = red[0] + red[1] + red[2] + red[3];

    float L = M + logf(S);
    for (int v = threadIdx.x; v < V; v += 256) out[row + v] -= L;
}

// ---------------- copy final hidden state to output tail ----------------
__global__ __launch_bounds__(256)
void copy_h_kernel(const float* __restrict__ h, float* __restrict__ out) {
    int i = blockIdx.x * 256 + threadIdx.x;   // 32768 elements
    out[OUT_LOGITS + i] = h[i];
}

}  // namespace

extern "C" void kernel_launch(void* const* d_in, const int* in_sizes, int n_in,
                              void* d_out, int out_size, void* d_ws, size_t ws_size,
                              hipStream_t stream) {
    // d_in: 0 encoder_outputs (unused), 1 encoder_hidden [1,B,H], 2 emb [V,H],
    //       3 W_ih [3H,H], 4 W_hh [3H,H], 5 b_ih [3H], 6 b_hh [3H],
    //       7 W_out [V,H], 8 b_out [V]
    const float* enc_hidden = (const float*)d_in[1];
    const float* emb   = (const float*)d_in[2];
    const float* W_ih  = (const float*)d_in[3];
    const float* W_hh  = (const float*)d_in[4];
    const float* b_ih  = (const float*)d_in[5];
    const float* b_hh  = (const float*)d_in[6];
    const float* W_out = (const float*)d_in[7];
    const float* b_out = (const float*)d_in[8];
    float* out = (float*)d_out;

    float* ws = (float*)d_ws;
    // ws layout (floats): WT (V*H) | hA | hB | hTA | hTB | amax(u64 [B][NPART])
    // (hA must directly follow WT: logits' last w-prefetch overruns WT by 1 row)
    const size_t WT_FLOATS = (size_t)V * H;              // 32,768,000
    float* WT   = ws;
    float* hA   = ws + WT_FLOATS;
    float* hB   = hA + 32768;
    float* hTA  = hB + 32768;
    float* hTB  = hTA + 32768;
    uint64_t* amax = (uint64_t*)(hTB + 32768);           // 32*500*8 B = 128 KB

    transpose_kernel<<<dim3(1000, 32), 256, 0, stream>>>(W_out, WT);

    for (int t = 0; t < T; ++t) {
        const float* hp = (t == 0) ? enc_hidden : ((t & 1) ? hA : hB);
        float* hn  = (t & 1) ? hB : hA;
        float* hnT = (t & 1) ? hTB : hTA;
        gru_kernel<<<H, 1024, 0, stream>>>(hp, emb, W_ih, W_hh, b_ih, b_hh,
                                           amax, t == 0 ? 0 : 1, hn, hnT);
        logits_fused_kernel<<<500, 512, 0, stream>>>(WT, hnT, b_out, out, t, amax);
    }

    logsoftmax_kernel<<<B * T, 256, 0, stream>>>(out);
    copy_h_kernel<<<32768 / 256, 256, 0, stream>>>(hB, out);  // t=63 wrote hB
}